// Round 1
// baseline (724.657 us; speedup 1.0000x reference)
//
#include <hip/hip_runtime.h>
#include <math.h>

// Problem constants (fixed by reference):
// B=4, N=2048, D=512, H=4, LH=AH=64, T=6400, lengths {2048,1536,1024,1792} (all %64==0)
// h layout per token (1024 cols): u[0:256) v[256:512) q[512:768) k[768:1024), head h at +h*64

__device__ __forceinline__ float silu_f(float v) {
    return v / (1.0f + __expf(-v));
}

// ---------------- K1: xn = layernorm(x) over D=512 ----------------
__global__ __launch_bounds__(256) void k1_ln(const float* __restrict__ x,
                                             float* __restrict__ xn) {
    const int row = blockIdx.x;
    const int tid = threadIdx.x;
    const float* xr = x + row * 512;
    float a = xr[tid];
    float b = xr[tid + 256];
    float s = a + b, ss = a * a + b * b;
#pragma unroll
    for (int off = 32; off > 0; off >>= 1) {
        s += __shfl_down(s, off);
        ss += __shfl_down(ss, off);
    }
    __shared__ float red[8];
    if ((tid & 63) == 0) { red[tid >> 6] = s; red[4 + (tid >> 6)] = ss; }
    __syncthreads();
    s = red[0] + red[1] + red[2] + red[3];
    ss = red[4] + red[5] + red[6] + red[7];
    const float mean = s * (1.0f / 512.0f);
    const float var = ss * (1.0f / 512.0f) - mean * mean;  // biased, matches jnp.var
    const float rstd = rsqrtf(var + 1e-6f);
    float* xo = xn + row * 512;
    xo[tid] = (a - mean) * rstd;
    xo[tid + 256] = (b - mean) * rstd;
}

// ---------------- K2: h = silu(xn @ uvqk)  [6400,512]x[512,1024] ----------------
__global__ __launch_bounds__(256) void k2_gemm1(const float* __restrict__ A,
                                                const float* __restrict__ Bg,
                                                float* __restrict__ C) {
    __shared__ __align__(16) float As[64][20];  // [m][k], stride 80B (16B-aligned)
    __shared__ __align__(16) float Bs[16][68];  // [k][n], stride 272B
    const int tid = threadIdx.x;
    const int bm = blockIdx.y * 64;
    const int bn = blockIdx.x * 64;
    const int ty = tid >> 4, tx = tid & 15;
    const int ar = tid >> 2, ac = (tid & 3) * 4;
    const int br = tid >> 4, bc = (tid & 15) * 4;
    float acc[4][4] = {};
    for (int kt = 0; kt < 512; kt += 16) {
        __syncthreads();
        *(float4*)&As[ar][ac] = *(const float4*)(A + (bm + ar) * 512 + kt + ac);
        *(float4*)&Bs[br][bc] = *(const float4*)(Bg + (kt + br) * 1024 + bn + bc);
        __syncthreads();
#pragma unroll
        for (int k4 = 0; k4 < 4; ++k4) {
            float a_[4][4], b_[4][4];
#pragma unroll
            for (int i = 0; i < 4; ++i) {
                float4 t = *(const float4*)&As[ty * 4 + i][k4 * 4];
                a_[i][0] = t.x; a_[i][1] = t.y; a_[i][2] = t.z; a_[i][3] = t.w;
            }
#pragma unroll
            for (int kk = 0; kk < 4; ++kk) {
                float4 t = *(const float4*)&Bs[k4 * 4 + kk][tx * 4];
                b_[kk][0] = t.x; b_[kk][1] = t.y; b_[kk][2] = t.z; b_[kk][3] = t.w;
            }
#pragma unroll
            for (int i = 0; i < 4; ++i)
#pragma unroll
                for (int j = 0; j < 4; ++j)
#pragma unroll
                    for (int kk = 0; kk < 4; ++kk)
                        acc[i][j] += a_[i][kk] * b_[kk][j];
        }
    }
#pragma unroll
    for (int i = 0; i < 4; ++i) {
        float4 o;
        o.x = silu_f(acc[i][0]);
        o.y = silu_f(acc[i][1]);
        o.z = silu_f(acc[i][2]);
        o.w = silu_f(acc[i][3]);
        *(float4*)(C + (bm + ty * 4 + i) * 1024 + bn + tx * 4) = o;
    }
}

// ---------------- K3: fused jagged SiLU attention ----------------
// grid (32 qtiles, B=4, H=4); block computes 64 queries x 64 LH outputs for one head
__global__ __launch_bounds__(256) void k3_attn(const float* __restrict__ h,
                                               const int* __restrict__ ts,
                                               const float* __restrict__ tsw,
                                               const int* __restrict__ offs,
                                               float* __restrict__ attn) {
    const int qt = blockIdx.x;
    const int b = blockIdx.y;
    const int hd = blockIdx.z;
    const int off = offs[b];
    const int len = offs[b + 1] - off;
    const int q0 = qt * 64;
    if (q0 >= len) return;  // lengths are multiples of 64 -> no partial tiles

    __shared__ __align__(16) float Qs[64][68];
    __shared__ __align__(16) float Ks[64][68];
    __shared__ __align__(16) float Vs[64][68];
    __shared__ __align__(16) float Ps[64][68];
    __shared__ int tq[64];
    __shared__ int tk[64];
    __shared__ float tw[129];

    const int tid = threadIdx.x;
    const int ty = tid >> 4, tx = tid & 15;
    const int lr = tid >> 4;        // 0..15
    const int lc = (tid & 15) * 4;  // float4 column

    if (tid < 129) tw[tid] = tsw[tid];
    if (tid < 64) tq[tid] = ts[b * 2048 + q0 + tid];

#pragma unroll
    for (int i = 0; i < 4; ++i) {
        const int r = lr + i * 16;
        *(float4*)&Qs[r][lc] =
            *(const float4*)(h + (off + q0 + r) * 1024 + 512 + hd * 64 + lc);
    }

    float oacc[4][4] = {};

    for (int kt = 0; kt <= qt; ++kt) {
        const int m0 = kt * 64;
        __syncthreads();  // previous PV stage done before overwriting Ks/Vs
#pragma unroll
        for (int i = 0; i < 4; ++i) {
            const int r = lr + i * 16;
            *(float4*)&Ks[r][lc] =
                *(const float4*)(h + (off + m0 + r) * 1024 + 768 + hd * 64 + lc);
            *(float4*)&Vs[r][lc] =
                *(const float4*)(h + (off + m0 + r) * 1024 + 256 + hd * 64 + lc);
        }
        if (tid < 64) tk[tid] = ts[b * 2048 + m0 + tid];
        __syncthreads();  // tiles ready

        // S = Q @ K^T (4x4 per thread)
        float sacc[4][4] = {};
#pragma unroll 4
        for (int k4 = 0; k4 < 16; ++k4) {
            float qa[4][4], kb[4][4];
#pragma unroll
            for (int i = 0; i < 4; ++i) {
                float4 t = *(const float4*)&Qs[ty * 4 + i][k4 * 4];
                qa[i][0] = t.x; qa[i][1] = t.y; qa[i][2] = t.z; qa[i][3] = t.w;
            }
#pragma unroll
            for (int j = 0; j < 4; ++j) {
                float4 t = *(const float4*)&Ks[tx * 4 + j][k4 * 4];
                kb[j][0] = t.x; kb[j][1] = t.y; kb[j][2] = t.z; kb[j][3] = t.w;
            }
#pragma unroll
            for (int i = 0; i < 4; ++i)
#pragma unroll
                for (int j = 0; j < 4; ++j)
#pragma unroll
                    for (int kk = 0; kk < 4; ++kk)
                        sacc[i][j] += qa[i][kk] * kb[j][kk];
        }

        // bias + silu/N + causal mask -> Ps
#pragma unroll
        for (int i = 0; i < 4; ++i) {
            const int n = q0 + ty * 4 + i;
            float p[4];
#pragma unroll
            for (int j = 0; j < 4; ++j) {
                const int m = m0 + tx * 4 + j;
                const float delta = fabsf((float)(tq[ty * 4 + i] - tk[tx * 4 + j]));
                int bucket = (int)floorf(log1pf(delta));
                bucket = bucket < 0 ? 0 : (bucket > 128 ? 128 : bucket);
                float v = sacc[i][j] + tw[bucket];
                v = silu_f(v) * (1.0f / 2048.0f);
                p[j] = (m <= n) ? v : 0.0f;
            }
            *(float4*)&Ps[ty * 4 + i][tx * 4] = make_float4(p[0], p[1], p[2], p[3]);
        }
        __syncthreads();  // Ps ready

        // O += P @ V
#pragma unroll 4
        for (int c4 = 0; c4 < 16; ++c4) {
            float pa[4][4], vb[4][4];
#pragma unroll
            for (int i = 0; i < 4; ++i) {
                float4 t = *(const float4*)&Ps[ty * 4 + i][c4 * 4];
                pa[i][0] = t.x; pa[i][1] = t.y; pa[i][2] = t.z; pa[i][3] = t.w;
            }
#pragma unroll
            for (int kk = 0; kk < 4; ++kk) {
                float4 t = *(const float4*)&Vs[c4 * 4 + kk][tx * 4];
                vb[kk][0] = t.x; vb[kk][1] = t.y; vb[kk][2] = t.z; vb[kk][3] = t.w;
            }
#pragma unroll
            for (int i = 0; i < 4; ++i)
#pragma unroll
                for (int j = 0; j < 4; ++j)
#pragma unroll
                    for (int kk = 0; kk < 4; ++kk)
                        oacc[i][j] += pa[i][kk] * vb[kk][j];
        }
    }

#pragma unroll
    for (int i = 0; i < 4; ++i) {
        *(float4*)(attn + (off + q0 + ty * 4 + i) * 256 + hd * 64 + tx * 4) =
            make_float4(oacc[i][0], oacc[i][1], oacc[i][2], oacc[i][3]);
    }
}

// ---------------- K4a: o_in = u * layernorm(attn_j) over 256 ----------------
__global__ __launch_bounds__(256) void k4a_ln(const float* __restrict__ attn,
                                              const float* __restrict__ h,
                                              float* __restrict__ o_in) {
    const int row = blockIdx.x;
    const int tid = threadIdx.x;
    float a = attn[row * 256 + tid];
    float s = a, ss = a * a;
#pragma unroll
    for (int off = 32; off > 0; off >>= 1) {
        s += __shfl_down(s, off);
        ss += __shfl_down(ss, off);
    }
    __shared__ float red[8];
    if ((tid & 63) == 0) { red[tid >> 6] = s; red[4 + (tid >> 6)] = ss; }
    __syncthreads();
    s = red[0] + red[1] + red[2] + red[3];
    ss = red[4] + red[5] + red[6] + red[7];
    const float mean = s * (1.0f / 256.0f);
    const float var = ss * (1.0f / 256.0f) - mean * mean;
    const float rstd = rsqrtf(var + 1e-6f);
    const float u = h[row * 1024 + tid];  // u = h cols [0,256)
    o_in[row * 256 + tid] = u * (a - mean) * rstd;
}

// ---------------- K4b: out = o_in @ o_w^T + o_b + x  [6400,256]x[256,512] ----------------
__global__ __launch_bounds__(256) void k4b_gemm2(const float* __restrict__ A,
                                                 const float* __restrict__ ow,
                                                 const float* __restrict__ ob,
                                                 const float* __restrict__ x,
                                                 float* __restrict__ out) {
    __shared__ __align__(16) float As[64][20];
    __shared__ __align__(16) float Bs[16][68];  // Bs[k][d] = ow[d][k] (transposed on load)
    const int tid = threadIdx.x;
    const int bm = blockIdx.y * 64;
    const int bn = blockIdx.x * 64;
    const int ty = tid >> 4, tx = tid & 15;
    const int ar = tid >> 2, ac = (tid & 3) * 4;
    const int wd = tid >> 2, wc = (tid & 3) * 4;
    float acc[4][4] = {};
    for (int kt = 0; kt < 256; kt += 16) {
        __syncthreads();
        *(float4*)&As[ar][ac] = *(const float4*)(A + (bm + ar) * 256 + kt + ac);
        float4 wv = *(const float4*)(ow + (bn + wd) * 256 + kt + wc);
        Bs[wc + 0][wd] = wv.x;
        Bs[wc + 1][wd] = wv.y;
        Bs[wc + 2][wd] = wv.z;
        Bs[wc + 3][wd] = wv.w;
        __syncthreads();
#pragma unroll
        for (int k4 = 0; k4 < 4; ++k4) {
            float a_[4][4], b_[4][4];
#pragma unroll
            for (int i = 0; i < 4; ++i) {
                float4 t = *(const float4*)&As[ty * 4 + i][k4 * 4];
                a_[i][0] = t.x; a_[i][1] = t.y; a_[i][2] = t.z; a_[i][3] = t.w;
            }
#pragma unroll
            for (int kk = 0; kk < 4; ++kk) {
                float4 t = *(const float4*)&Bs[k4 * 4 + kk][tx * 4];
                b_[kk][0] = t.x; b_[kk][1] = t.y; b_[kk][2] = t.z; b_[kk][3] = t.w;
            }
#pragma unroll
            for (int i = 0; i < 4; ++i)
#pragma unroll
                for (int j = 0; j < 4; ++j)
#pragma unroll
                    for (int kk = 0; kk < 4; ++kk)
                        acc[i][j] += a_[i][kk] * b_[kk][j];
        }
    }
#pragma unroll
    for (int i = 0; i < 4; ++i) {
        const int r = bm + ty * 4 + i;
        const int c = bn + tx * 4;
        float4 xv = *(const float4*)(x + r * 512 + c);
        float4 bv = *(const float4*)(ob + c);
        float4 o;
        o.x = acc[i][0] + bv.x + xv.x;
        o.y = acc[i][1] + bv.y + xv.y;
        o.z = acc[i][2] + bv.z + xv.z;
        o.w = acc[i][3] + bv.w + xv.w;
        *(float4*)(out + r * 512 + c) = o;
    }
}

extern "C" void kernel_launch(void* const* d_in, const int* in_sizes, int n_in,
                              void* d_out, int out_size, void* d_ws, size_t ws_size,
                              hipStream_t stream) {
    const float* x = (const float*)d_in[0];       // [6400,512]
    const float* uvqk = (const float*)d_in[1];    // [512,1024]
    const float* ow = (const float*)d_in[2];      // [512,256]
    const float* ob = (const float*)d_in[3];      // [512]
    const float* tsw = (const float*)d_in[4];     // [129]
    const int* ts = (const int*)d_in[5];          // [4,2048]
    // d_in[6] invalid_attn_mask: pure tril -> implemented as m<=n, not read
    const int* offs = (const int*)d_in[7];        // [5]
    float* out = (float*)d_out;                   // [6400,512]

    float* ws = (float*)d_ws;
    float* xn = ws;                      // 6400*512
    float* h = xn + 6400 * 512;          // 6400*1024
    float* attn = h + 6400 * 1024;       // 6400*256
    float* o_in = attn + 6400 * 256;     // 6400*256
    // total ws use: 13,107,200 floats = 52.4 MB

    k1_ln<<<6400, 256, 0, stream>>>(x, xn);
    k2_gemm1<<<dim3(16, 100), 256, 0, stream>>>(xn, uvqk, h);
    k3_attn<<<dim3(32, 4, 4), 256, 0, stream>>>(h, ts, tsw, offs, attn);
    k4a_ln<<<6400, 256, 0, stream>>>(attn, h, o_in);
    k4b_gemm2<<<dim3(8, 100), 256, 0, stream>>>(o_in, ow, ob, x, out);
}

// Round 3
// 348.443 us; speedup vs baseline: 2.0797x; 2.0797x over previous
//
#include <hip/hip_runtime.h>
#include <math.h>

// Problem constants (fixed by reference):
// B=4, N=2048, D=512, H=4, LH=AH=64, T=6400, lengths {2048,1536,1024,1792} (all %64==0)
// h cols (1024): u[0:256) v[256:512) q[512:768) k[768:1024)
// hb (bf16 copy, 768 cols): v[0:256) q[256:512) k[512:768), head hd at +hd*64

typedef __attribute__((ext_vector_type(8))) short bf16x8;   // 8 bf16 in 4 VGPRs
typedef __attribute__((ext_vector_type(4))) float f32x4;

__device__ __forceinline__ float silu_f(float v) {
    return v / (1.0f + __expf(-v));
}

__device__ __forceinline__ unsigned short f2bf(float f) {  // RNE float->bf16
    unsigned int u = __float_as_uint(f);
    u += 0x7fffu + ((u >> 16) & 1u);
    return (unsigned short)(u >> 16);
}

// ---------------- K1: xn = layernorm(x) over D=512 ----------------
__global__ __launch_bounds__(256) void k1_ln(const float* __restrict__ x,
                                             float* __restrict__ xn) {
    const int row = blockIdx.x;
    const int tid = threadIdx.x;
    const float* xr = x + row * 512;
    float a = xr[tid];
    float b = xr[tid + 256];
    float s = a + b, ss = a * a + b * b;
#pragma unroll
    for (int off = 32; off > 0; off >>= 1) {
        s += __shfl_down(s, off);
        ss += __shfl_down(ss, off);
    }
    __shared__ float red[8];
    if ((tid & 63) == 0) { red[tid >> 6] = s; red[4 + (tid >> 6)] = ss; }
    __syncthreads();
    s = red[0] + red[1] + red[2] + red[3];
    ss = red[4] + red[5] + red[6] + red[7];
    const float mean = s * (1.0f / 512.0f);
    const float var = ss * (1.0f / 512.0f) - mean * mean;  // biased, matches jnp.var
    const float rstd = rsqrtf(var + 1e-6f);
    float* xo = xn + row * 512;
    xo[tid] = (a - mean) * rstd;
    xo[tid + 256] = (b - mean) * rstd;
}

// ---------------- K2: h = silu(xn @ uvqk); u -> fp32, v/q/k -> bf16 ----------------
__global__ __launch_bounds__(256) void k2_gemm1(const float* __restrict__ A,
                                                const float* __restrict__ Bg,
                                                float* __restrict__ u_out,
                                                unsigned short* __restrict__ hb) {
    __shared__ __align__(16) float As[64][20];
    __shared__ __align__(16) float Bs[16][68];
    const int tid = threadIdx.x;
    const int bm = blockIdx.y * 64;
    const int bn = blockIdx.x * 64;
    const int ty = tid >> 4, tx = tid & 15;
    const int ar = tid >> 2, ac = (tid & 3) * 4;
    const int br = tid >> 4, bc = (tid & 15) * 4;
    float acc[4][4] = {};
    for (int kt = 0; kt < 512; kt += 16) {
        __syncthreads();
        *(float4*)&As[ar][ac] = *(const float4*)(A + (bm + ar) * 512 + kt + ac);
        *(float4*)&Bs[br][bc] = *(const float4*)(Bg + (kt + br) * 1024 + bn + bc);
        __syncthreads();
#pragma unroll
        for (int k4 = 0; k4 < 4; ++k4) {
            float a_[4][4], b_[4][4];
#pragma unroll
            for (int i = 0; i < 4; ++i) {
                float4 t = *(const float4*)&As[ty * 4 + i][k4 * 4];
                a_[i][0] = t.x; a_[i][1] = t.y; a_[i][2] = t.z; a_[i][3] = t.w;
            }
#pragma unroll
            for (int kk = 0; kk < 4; ++kk) {
                float4 t = *(const float4*)&Bs[k4 * 4 + kk][tx * 4];
                b_[kk][0] = t.x; b_[kk][1] = t.y; b_[kk][2] = t.z; b_[kk][3] = t.w;
            }
#pragma unroll
            for (int i = 0; i < 4; ++i)
#pragma unroll
                for (int j = 0; j < 4; ++j)
#pragma unroll
                    for (int kk = 0; kk < 4; ++kk)
                        acc[i][j] += a_[i][kk] * b_[kk][j];
        }
    }
    if (bn < 256) {  // u region -> fp32
#pragma unroll
        for (int i = 0; i < 4; ++i) {
            float4 o;
            o.x = silu_f(acc[i][0]);
            o.y = silu_f(acc[i][1]);
            o.z = silu_f(acc[i][2]);
            o.w = silu_f(acc[i][3]);
            *(float4*)(u_out + (bm + ty * 4 + i) * 256 + bn + tx * 4) = o;
        }
    } else {  // v/q/k -> bf16
#pragma unroll
        for (int i = 0; i < 4; ++i) {
            ushort4 o;
            o.x = f2bf(silu_f(acc[i][0]));
            o.y = f2bf(silu_f(acc[i][1]));
            o.z = f2bf(silu_f(acc[i][2]));
            o.w = f2bf(silu_f(acc[i][3]));
            *(ushort4*)(hb + (bm + ty * 4 + i) * 768 + (bn - 256) + tx * 4) = o;
        }
    }
}

// ---------------- K3: fused jagged SiLU attention (bf16 MFMA) ----------------
// block = one (batch, head, 64-query tile); 4 waves, each owns 16 query rows
__global__ __launch_bounds__(256, 4) void k3_attn(const unsigned short* __restrict__ hb,
                                                  const int* __restrict__ ts,
                                                  const float* __restrict__ tsw,
                                                  const int* __restrict__ offs,
                                                  float* __restrict__ attn) {
    const int b = blockIdx.y;
    const int hd = blockIdx.z;
    const int off = offs[b];
    const int len = offs[b + 1] - off;
    const int nqt = len >> 6;
    const int qt = nqt - 1 - blockIdx.x;  // longest work first
    if (qt < 0) return;
    const int q0 = qt * 64;

    __shared__ __align__(16) unsigned short Qs[64][72];
    __shared__ __align__(16) unsigned short Ks[64][72];
    __shared__ __align__(16) unsigned short Vt[64][72];  // [lh][key]
    __shared__ __align__(16) unsigned short Ps[64][72];  // [query][key]
    __shared__ float tqf[64], tkf[64];
    __shared__ float tw[132];

    const int tid = threadIdx.x;
    const int lane = tid & 63;
    const int w = tid >> 6;        // wave id: query rows [w*16, w*16+16)
    const int l15 = lane & 15;
    const int quad = lane >> 4;

    if (tid < 129) tw[tid] = tsw[tid];
    if (tid < 64) tqf[tid] = (float)ts[b * 2048 + q0 + tid];
    // 64x64 bf16 tile = 4096 elems; 256 threads x uint4(8 elems) covers half ->
    // MUST loop twice (round-2 bug: single pass left rows 32..63 uninitialized)
#pragma unroll
    for (int i = 0; i < 2; ++i) {
        const int r = (tid >> 3) + i * 32;
        const int c = (tid & 7) * 8;
        *(uint4*)&Qs[r][c] = *(const uint4*)(hb + (off + q0 + r) * 768 + 256 + hd * 64 + c);
    }
    __syncthreads();

    // Q A-fragments: fixed for the whole key loop
    const bf16x8 aQ0 = *(const bf16x8*)&Qs[w * 16 + l15][quad * 8];
    const bf16x8 aQ1 = *(const bf16x8*)&Qs[w * 16 + l15][32 + quad * 8];
    const f32x4 tq4 = *(const f32x4*)&tqf[w * 16 + quad * 4];  // rows quad*4+reg
    const int nbase = q0 + w * 16 + quad * 4;

    f32x4 oacc[4] = {};

    for (int kt = 0; kt <= qt; ++kt) {
        const int m0 = kt * 64;
        __syncthreads();  // prior PV reads of Ks/Vt done
#pragma unroll
        for (int i = 0; i < 2; ++i) {
            const int r = (tid >> 3) + i * 32;
            const int c = (tid & 7) * 8;
            *(uint4*)&Ks[r][c] = *(const uint4*)(hb + (off + m0 + r) * 768 + 512 + hd * 64 + c);
            uint4 vv = *(const uint4*)(hb + (off + m0 + r) * 768 + hd * 64 + c);
            const unsigned short* vs = (const unsigned short*)&vv;
#pragma unroll
            for (int j = 0; j < 8; ++j) Vt[c + j][r] = vs[j];  // transpose V
        }
        if (tid < 64) tkf[tid] = (float)ts[b * 2048 + m0 + tid];
        __syncthreads();

        // S = Q @ K^T : wave computes 16 queries x 64 keys
        f32x4 s[4] = {};
#pragma unroll
        for (int nt = 0; nt < 4; ++nt) {
            bf16x8 b0 = *(const bf16x8*)&Ks[nt * 16 + l15][quad * 8];
            bf16x8 b1 = *(const bf16x8*)&Ks[nt * 16 + l15][32 + quad * 8];
            s[nt] = __builtin_amdgcn_mfma_f32_16x16x32_bf16(aQ0, b0, s[nt], 0, 0, 0);
            s[nt] = __builtin_amdgcn_mfma_f32_16x16x32_bf16(aQ1, b1, s[nt], 0, 0, 0);
        }

        // bias + silu/N + causal mask -> Ps (bf16), each wave writes its own 16 rows
#pragma unroll
        for (int nt = 0; nt < 4; ++nt) {
            const int m = m0 + nt * 16 + l15;
            const float tk = tkf[nt * 16 + l15];
#pragma unroll
            for (int reg = 0; reg < 4; ++reg) {
                const int n = nbase + reg;
                const float delta = fabsf(tq4[reg] - tk);
                int bucket = (int)floorf(__log2f(1.0f + delta) * 0.6931471805599453f);
                bucket = bucket < 0 ? 0 : (bucket > 128 ? 128 : bucket);
                float val = s[nt][reg] + tw[bucket];
                val = silu_f(val) * (1.0f / 2048.0f);
                val = (m <= n) ? val : 0.0f;
                Ps[w * 16 + quad * 4 + reg][nt * 16 + l15] = f2bf(val);
            }
        }
        // wave reads back only its own Ps rows -> intra-wave lgkmcnt suffices, no barrier

        // O += P @ V
        const bf16x8 aP0 = *(const bf16x8*)&Ps[w * 16 + l15][quad * 8];
        const bf16x8 aP1 = *(const bf16x8*)&Ps[w * 16 + l15][32 + quad * 8];
#pragma unroll
        for (int nt = 0; nt < 4; ++nt) {
            bf16x8 v0 = *(const bf16x8*)&Vt[nt * 16 + l15][quad * 8];
            bf16x8 v1 = *(const bf16x8*)&Vt[nt * 16 + l15][32 + quad * 8];
            oacc[nt] = __builtin_amdgcn_mfma_f32_16x16x32_bf16(aP0, v0, oacc[nt], 0, 0, 0);
            oacc[nt] = __builtin_amdgcn_mfma_f32_16x16x32_bf16(aP1, v1, oacc[nt], 0, 0, 0);
        }
    }

    // write O: row = off+q0+w*16+quad*4+reg, col = hd*64 + nt*16 + l15
#pragma unroll
    for (int nt = 0; nt < 4; ++nt)
#pragma unroll
        for (int reg = 0; reg < 4; ++reg)
            attn[(off + q0 + w * 16 + quad * 4 + reg) * 256 + hd * 64 + nt * 16 + l15] =
                oacc[nt][reg];
}

// ---------------- K4a: o_in = u * layernorm(attn_j) over 256 ----------------
__global__ __launch_bounds__(256) void k4a_ln(const float* __restrict__ attn,
                                              const float* __restrict__ u_in,
                                              float* __restrict__ o_in) {
    const int row = blockIdx.x;
    const int tid = threadIdx.x;
    float a = attn[row * 256 + tid];
    float s = a, ss = a * a;
#pragma unroll
    for (int off = 32; off > 0; off >>= 1) {
        s += __shfl_down(s, off);
        ss += __shfl_down(ss, off);
    }
    __shared__ float red[8];
    if ((tid & 63) == 0) { red[tid >> 6] = s; red[4 + (tid >> 6)] = ss; }
    __syncthreads();
    s = red[0] + red[1] + red[2] + red[3];
    ss = red[4] + red[5] + red[6] + red[7];
    const float mean = s * (1.0f / 256.0f);
    const float var = ss * (1.0f / 256.0f) - mean * mean;
    const float rstd = rsqrtf(var + 1e-6f);
    const float u = u_in[row * 256 + tid];
    o_in[row * 256 + tid] = u * (a - mean) * rstd;
}

// ---------------- K4b: out = o_in @ o_w^T + o_b + x  [6400,256]x[256,512] ----------------
__global__ __launch_bounds__(256) void k4b_gemm2(const float* __restrict__ A,
                                                 const float* __restrict__ ow,
                                                 const float* __restrict__ ob,
                                                 const float* __restrict__ x,
                                                 float* __restrict__ out) {
    __shared__ __align__(16) float As[64][20];
    __shared__ __align__(16) float Bs[16][68];  // Bs[k][d] = ow[d][k]
    const int tid = threadIdx.x;
    const int bm = blockIdx.y * 64;
    const int bn = blockIdx.x * 64;
    const int ty = tid >> 4, tx = tid & 15;
    const int ar = tid >> 2, ac = (tid & 3) * 4;
    const int wd = tid >> 2, wc = (tid & 3) * 4;
    float acc[4][4] = {};
    for (int kt = 0; kt < 256; kt += 16) {
        __syncthreads();
        *(float4*)&As[ar][ac] = *(const float4*)(A + (bm + ar) * 256 + kt + ac);
        float4 wv = *(const float4*)(ow + (bn + wd) * 256 + kt + wc);
        Bs[wc + 0][wd] = wv.x;
        Bs[wc + 1][wd] = wv.y;
        Bs[wc + 2][wd] = wv.z;
        Bs[wc + 3][wd] = wv.w;
        __syncthreads();
#pragma unroll
        for (int k4 = 0; k4 < 4; ++k4) {
            float a_[4][4], b_[4][4];
#pragma unroll
            for (int i = 0; i < 4; ++i) {
                float4 t = *(const float4*)&As[ty * 4 + i][k4 * 4];
                a_[i][0] = t.x; a_[i][1] = t.y; a_[i][2] = t.z; a_[i][3] = t.w;
            }
#pragma unroll
            for (int kk = 0; kk < 4; ++kk) {
                float4 t = *(const float4*)&Bs[k4 * 4 + kk][tx * 4];
                b_[kk][0] = t.x; b_[kk][1] = t.y; b_[kk][2] = t.z; b_[kk][3] = t.w;
            }
#pragma unroll
            for (int i = 0; i < 4; ++i)
#pragma unroll
                for (int j = 0; j < 4; ++j)
#pragma unroll
                    for (int kk = 0; kk < 4; ++kk)
                        acc[i][j] += a_[i][kk] * b_[kk][j];
        }
    }
#pragma unroll
    for (int i = 0; i < 4; ++i) {
        const int r = bm + ty * 4 + i;
        const int c = bn + tx * 4;
        float4 xv = *(const float4*)(x + r * 512 + c);
        float4 bv = *(const float4*)(ob + c);
        float4 o;
        o.x = acc[i][0] + bv.x + xv.x;
        o.y = acc[i][1] + bv.y + xv.y;
        o.z = acc[i][2] + bv.z + xv.z;
        o.w = acc[i][3] + bv.w + xv.w;
        *(float4*)(out + r * 512 + c) = o;
    }
}

extern "C" void kernel_launch(void* const* d_in, const int* in_sizes, int n_in,
                              void* d_out, int out_size, void* d_ws, size_t ws_size,
                              hipStream_t stream) {
    const float* x = (const float*)d_in[0];       // [6400,512]
    const float* uvqk = (const float*)d_in[1];    // [512,1024]
    const float* ow = (const float*)d_in[2];      // [512,256]
    const float* ob = (const float*)d_in[3];      // [512]
    const float* tsw = (const float*)d_in[4];     // [129]
    const int* ts = (const int*)d_in[5];          // [4,2048]
    // d_in[6] invalid_attn_mask: pure tril -> implemented as m<=n, not read
    const int* offs = (const int*)d_in[7];        // [5]
    float* out = (float*)d_out;                   // [6400,512]

    float* ws = (float*)d_ws;
    float* xn = ws;                               // 6400*512 f32
    float* u = xn + 6400 * 512;                   // 6400*256 f32
    float* attn = u + 6400 * 256;                 // 6400*256 f32
    float* o_in = attn + 6400 * 256;              // 6400*256 f32
    unsigned short* hb = (unsigned short*)(o_in + 6400 * 256);  // 6400*768 bf16
    // total ws use: ~39 MB

    k1_ln<<<6400, 256, 0, stream>>>(x, xn);
    k2_gemm1<<<dim3(16, 100), 256, 0, stream>>>(xn, uvqk, u, hb);
    k3_attn<<<dim3(32, 4, 4), 256, 0, stream>>>(hb, ts, tsw, offs, attn);
    k4a_ln<<<6400, 256, 0, stream>>>(attn, u, o_in);
    k4b_gemm2<<<dim3(8, 100), 256, 0, stream>>>(o_in, ow, ob, x, out);
}

// Round 4
// 233.347 us; speedup vs baseline: 3.1055x; 1.4932x over previous
//
#include <hip/hip_runtime.h>
#include <math.h>

// Problem constants (fixed by reference):
// B=4, N=2048, D=512, H=4, LH=AH=64, T=6400, lengths {2048,1536,1024,1792} (all %64==0)
// hb (bf16, 768 cols): v[0:256) q[256:512) k[512:768), head hd at +hd*64

typedef __attribute__((ext_vector_type(8))) short bf16x8;   // 8 bf16 in 4 VGPRs
typedef __attribute__((ext_vector_type(4))) float f32x4;

__device__ __forceinline__ float silu_f(float v) {
    return v / (1.0f + __expf(-v));
}

__device__ __forceinline__ unsigned short f2bf(float f) {  // RNE float->bf16
    unsigned int u = __float_as_uint(f);
    u += 0x7fffu + ((u >> 16) & 1u);
    return (unsigned short)(u >> 16);
}

// ---------------- K0a: uvqkT[n][k] = bf16(uvqk[k][n])  (512x1024 -> 1024x512) ----------------
__global__ __launch_bounds__(256) void k0a_transpose_cast(const float* __restrict__ uvqk,
                                                          unsigned short* __restrict__ uvqkT) {
    __shared__ float L[64][68];
    const int n0 = blockIdx.x * 64;
    const int k0 = blockIdx.y * 64;
    const int tid = threadIdx.x;
#pragma unroll
    for (int i = 0; i < 4; ++i) {
        const int r = (tid >> 4) + i * 16;
        const int c = (tid & 15) * 4;
        *(float4*)&L[r][c] = *(const float4*)(uvqk + (k0 + r) * 1024 + n0 + c);
    }
    __syncthreads();
    const int n = tid >> 2;
    const int kb = (tid & 3) * 16;
#pragma unroll
    for (int pass = 0; pass < 2; ++pass) {
        unsigned short pk[8];
#pragma unroll
        for (int j = 0; j < 8; ++j) pk[j] = f2bf(L[kb + pass * 8 + j][n]);
        *(uint4*)(uvqkT + (n0 + n) * 512 + k0 + kb + pass * 8) = *(const uint4*)pk;
    }
}

// ---------------- K0b: owb = bf16(ow)  (512x256, already [d][k] k-contiguous) ----------------
__global__ __launch_bounds__(256) void k0b_cast_ow(const float* __restrict__ ow,
                                                   unsigned short* __restrict__ owb) {
    const int base = (blockIdx.x * 256 + threadIdx.x) * 8;
    float4 a = *(const float4*)(ow + base);
    float4 b = *(const float4*)(ow + base + 4);
    unsigned short pk[8] = {f2bf(a.x), f2bf(a.y), f2bf(a.z), f2bf(a.w),
                            f2bf(b.x), f2bf(b.y), f2bf(b.z), f2bf(b.w)};
    *(uint4*)(owb + base) = *(const uint4*)pk;
}

// ---------------- K1: xnb = bf16(layernorm(x)) over D=512 ----------------
__global__ __launch_bounds__(256) void k1_ln(const float* __restrict__ x,
                                             unsigned short* __restrict__ xnb) {
    const int row = blockIdx.x;
    const int tid = threadIdx.x;
    const float* xr = x + row * 512;
    float a = xr[tid];
    float b = xr[tid + 256];
    float s = a + b, ss = a * a + b * b;
#pragma unroll
    for (int off = 32; off > 0; off >>= 1) {
        s += __shfl_down(s, off);
        ss += __shfl_down(ss, off);
    }
    __shared__ float red[8];
    if ((tid & 63) == 0) { red[tid >> 6] = s; red[4 + (tid >> 6)] = ss; }
    __syncthreads();
    s = red[0] + red[1] + red[2] + red[3];
    ss = red[4] + red[5] + red[6] + red[7];
    const float mean = s * (1.0f / 512.0f);
    const float var = ss * (1.0f / 512.0f) - mean * mean;  // biased, matches jnp.var
    const float rstd = rsqrtf(var + 1e-6f);
    xnb[row * 512 + tid] = f2bf((a - mean) * rstd);
    xnb[row * 512 + tid + 256] = f2bf((b - mean) * rstd);
}

// ---------------- K2: h = silu(xn @ uvqk) via bf16 MFMA; u -> fp32, v/q/k -> bf16 ----------------
// tile 64x64, 4 waves; wave w: rows [w*16, w*16+16), all 64 cols; K=512 in 8 chunks
__global__ __launch_bounds__(256, 4) void k2_gemm1(const unsigned short* __restrict__ A,
                                                   const unsigned short* __restrict__ Bt,
                                                   float* __restrict__ u_out,
                                                   unsigned short* __restrict__ hb) {
    __shared__ __align__(16) unsigned short As[64][72];
    __shared__ __align__(16) unsigned short Bs[64][72];  // [n][k]
    const int tid = threadIdx.x;
    const int lane = tid & 63;
    const int w = tid >> 6;
    const int l15 = lane & 15;
    const int quad = lane >> 4;
    const int bm = blockIdx.y * 64;
    const int bn = blockIdx.x * 64;

    f32x4 acc[4] = {};
    for (int kc = 0; kc < 512; kc += 64) {
        __syncthreads();
#pragma unroll
        for (int i = 0; i < 2; ++i) {
            const int r = (tid >> 3) + i * 32;
            const int c = (tid & 7) * 8;
            *(uint4*)&As[r][c] = *(const uint4*)(A + (bm + r) * 512 + kc + c);
            *(uint4*)&Bs[r][c] = *(const uint4*)(Bt + (bn + r) * 512 + kc + c);
        }
        __syncthreads();
        const bf16x8 a0 = *(const bf16x8*)&As[w * 16 + l15][quad * 8];
        const bf16x8 a1 = *(const bf16x8*)&As[w * 16 + l15][32 + quad * 8];
#pragma unroll
        for (int nt = 0; nt < 4; ++nt) {
            bf16x8 b0 = *(const bf16x8*)&Bs[nt * 16 + l15][quad * 8];
            bf16x8 b1 = *(const bf16x8*)&Bs[nt * 16 + l15][32 + quad * 8];
            acc[nt] = __builtin_amdgcn_mfma_f32_16x16x32_bf16(a0, b0, acc[nt], 0, 0, 0);
            acc[nt] = __builtin_amdgcn_mfma_f32_16x16x32_bf16(a1, b1, acc[nt], 0, 0, 0);
        }
    }
    // epilogue: row m = bm + w*16 + quad*4 + reg, col = bn + nt*16 + l15
    const int m = bm + w * 16 + quad * 4;
    if (bn < 256) {
#pragma unroll
        for (int nt = 0; nt < 4; ++nt)
#pragma unroll
            for (int reg = 0; reg < 4; ++reg)
                u_out[(m + reg) * 256 + bn + nt * 16 + l15] = silu_f(acc[nt][reg]);
    } else {
#pragma unroll
        for (int nt = 0; nt < 4; ++nt)
#pragma unroll
            for (int reg = 0; reg < 4; ++reg)
                hb[(m + reg) * 768 + (bn - 256) + nt * 16 + l15] = f2bf(silu_f(acc[nt][reg]));
    }
}

// ---------------- K3: fused jagged SiLU attention (bf16 MFMA) ----------------
__global__ __launch_bounds__(256, 4) void k3_attn(const unsigned short* __restrict__ hb,
                                                  const int* __restrict__ ts,
                                                  const float* __restrict__ tsw,
                                                  const int* __restrict__ offs,
                                                  float* __restrict__ attn) {
    const int b = blockIdx.y;
    const int hd = blockIdx.z;
    const int off = offs[b];
    const int len = offs[b + 1] - off;
    const int nqt = len >> 6;
    const int qt = nqt - 1 - blockIdx.x;  // longest work first
    if (qt < 0) return;
    const int q0 = qt * 64;

    __shared__ __align__(16) unsigned short Qs[64][72];
    __shared__ __align__(16) unsigned short Ks[64][72];
    __shared__ __align__(16) unsigned short Vt[64][72];  // [lh][key]
    __shared__ __align__(16) unsigned short Ps[64][72];  // [query][key]
    __shared__ float tqf[64], tkf[64];
    __shared__ float tw[132];

    const int tid = threadIdx.x;
    const int lane = tid & 63;
    const int w = tid >> 6;
    const int l15 = lane & 15;
    const int quad = lane >> 4;

    if (tid < 129) tw[tid] = tsw[tid];
    if (tid < 64) tqf[tid] = (float)ts[b * 2048 + q0 + tid];
#pragma unroll
    for (int i = 0; i < 2; ++i) {
        const int r = (tid >> 3) + i * 32;
        const int c = (tid & 7) * 8;
        *(uint4*)&Qs[r][c] = *(const uint4*)(hb + (off + q0 + r) * 768 + 256 + hd * 64 + c);
    }
    __syncthreads();

    const bf16x8 aQ0 = *(const bf16x8*)&Qs[w * 16 + l15][quad * 8];
    const bf16x8 aQ1 = *(const bf16x8*)&Qs[w * 16 + l15][32 + quad * 8];
    const f32x4 tq4 = *(const f32x4*)&tqf[w * 16 + quad * 4];
    const int nbase = q0 + w * 16 + quad * 4;

    f32x4 oacc[4] = {};

    for (int kt = 0; kt <= qt; ++kt) {
        const int m0 = kt * 64;
        __syncthreads();
#pragma unroll
        for (int i = 0; i < 2; ++i) {
            const int r = (tid >> 3) + i * 32;
            const int c = (tid & 7) * 8;
            *(uint4*)&Ks[r][c] = *(const uint4*)(hb + (off + m0 + r) * 768 + 512 + hd * 64 + c);
            uint4 vv = *(const uint4*)(hb + (off + m0 + r) * 768 + hd * 64 + c);
            const unsigned short* vs = (const unsigned short*)&vv;
#pragma unroll
            for (int j = 0; j < 8; ++j) Vt[c + j][r] = vs[j];  // transpose V
        }
        if (tid < 64) tkf[tid] = (float)ts[b * 2048 + m0 + tid];
        __syncthreads();

        f32x4 s[4] = {};
#pragma unroll
        for (int nt = 0; nt < 4; ++nt) {
            bf16x8 b0 = *(const bf16x8*)&Ks[nt * 16 + l15][quad * 8];
            bf16x8 b1 = *(const bf16x8*)&Ks[nt * 16 + l15][32 + quad * 8];
            s[nt] = __builtin_amdgcn_mfma_f32_16x16x32_bf16(aQ0, b0, s[nt], 0, 0, 0);
            s[nt] = __builtin_amdgcn_mfma_f32_16x16x32_bf16(aQ1, b1, s[nt], 0, 0, 0);
        }

#pragma unroll
        for (int nt = 0; nt < 4; ++nt) {
            const int m = m0 + nt * 16 + l15;
            const float tk = tkf[nt * 16 + l15];
#pragma unroll
            for (int reg = 0; reg < 4; ++reg) {
                const int n = nbase + reg;
                const float delta = fabsf(tq4[reg] - tk);
                int bucket = (int)floorf(__log2f(1.0f + delta) * 0.6931471805599453f);
                bucket = bucket < 0 ? 0 : (bucket > 128 ? 128 : bucket);
                float val = s[nt][reg] + tw[bucket];
                val = silu_f(val) * (1.0f / 2048.0f);
                val = (m <= n) ? val : 0.0f;
                Ps[w * 16 + quad * 4 + reg][nt * 16 + l15] = f2bf(val);
            }
        }
        // wave reads back only its own Ps rows -> no barrier needed

        const bf16x8 aP0 = *(const bf16x8*)&Ps[w * 16 + l15][quad * 8];
        const bf16x8 aP1 = *(const bf16x8*)&Ps[w * 16 + l15][32 + quad * 8];
#pragma unroll
        for (int nt = 0; nt < 4; ++nt) {
            bf16x8 v0 = *(const bf16x8*)&Vt[nt * 16 + l15][quad * 8];
            bf16x8 v1 = *(const bf16x8*)&Vt[nt * 16 + l15][32 + quad * 8];
            oacc[nt] = __builtin_amdgcn_mfma_f32_16x16x32_bf16(aP0, v0, oacc[nt], 0, 0, 0);
            oacc[nt] = __builtin_amdgcn_mfma_f32_16x16x32_bf16(aP1, v1, oacc[nt], 0, 0, 0);
        }
    }

#pragma unroll
    for (int nt = 0; nt < 4; ++nt)
#pragma unroll
        for (int reg = 0; reg < 4; ++reg)
            attn[(off + q0 + w * 16 + quad * 4 + reg) * 256 + hd * 64 + nt * 16 + l15] =
                oacc[nt][reg];
}

// ---------------- K4a: o_in = bf16(u * layernorm(attn_j)) over 256 ----------------
__global__ __launch_bounds__(256) void k4a_ln(const float* __restrict__ attn,
                                              const float* __restrict__ u_in,
                                              unsigned short* __restrict__ o_in) {
    const int row = blockIdx.x;
    const int tid = threadIdx.x;
    float a = attn[row * 256 + tid];
    float s = a, ss = a * a;
#pragma unroll
    for (int off = 32; off > 0; off >>= 1) {
        s += __shfl_down(s, off);
        ss += __shfl_down(ss, off);
    }
    __shared__ float red[8];
    if ((tid & 63) == 0) { red[tid >> 6] = s; red[4 + (tid >> 6)] = ss; }
    __syncthreads();
    s = red[0] + red[1] + red[2] + red[3];
    ss = red[4] + red[5] + red[6] + red[7];
    const float mean = s * (1.0f / 256.0f);
    const float var = ss * (1.0f / 256.0f) - mean * mean;
    const float rstd = rsqrtf(var + 1e-6f);
    const float u = u_in[row * 256 + tid];
    o_in[row * 256 + tid] = f2bf(u * (a - mean) * rstd);
}

// ---------------- K4b: out = o_in @ o_w^T + o_b + x via bf16 MFMA ----------------
// A = o_in [6400,256] bf16; B = owb [512,256] ([d][k], k-contiguous); tile 64x64, 4 chunks
__global__ __launch_bounds__(256, 4) void k4b_gemm2(const unsigned short* __restrict__ A,
                                                    const unsigned short* __restrict__ owb,
                                                    const float* __restrict__ ob,
                                                    const float* __restrict__ x,
                                                    float* __restrict__ out) {
    __shared__ __align__(16) unsigned short As[64][72];
    __shared__ __align__(16) unsigned short Bs[64][72];  // [d][k]
    const int tid = threadIdx.x;
    const int lane = tid & 63;
    const int w = tid >> 6;
    const int l15 = lane & 15;
    const int quad = lane >> 4;
    const int bm = blockIdx.y * 64;
    const int bn = blockIdx.x * 64;

    f32x4 acc[4] = {};
    for (int kc = 0; kc < 256; kc += 64) {
        __syncthreads();
#pragma unroll
        for (int i = 0; i < 2; ++i) {
            const int r = (tid >> 3) + i * 32;
            const int c = (tid & 7) * 8;
            *(uint4*)&As[r][c] = *(const uint4*)(A + (bm + r) * 256 + kc + c);
            *(uint4*)&Bs[r][c] = *(const uint4*)(owb + (bn + r) * 256 + kc + c);
        }
        __syncthreads();
        const bf16x8 a0 = *(const bf16x8*)&As[w * 16 + l15][quad * 8];
        const bf16x8 a1 = *(const bf16x8*)&As[w * 16 + l15][32 + quad * 8];
#pragma unroll
        for (int nt = 0; nt < 4; ++nt) {
            bf16x8 b0 = *(const bf16x8*)&Bs[nt * 16 + l15][quad * 8];
            bf16x8 b1 = *(const bf16x8*)&Bs[nt * 16 + l15][32 + quad * 8];
            acc[nt] = __builtin_amdgcn_mfma_f32_16x16x32_bf16(a0, b0, acc[nt], 0, 0, 0);
            acc[nt] = __builtin_amdgcn_mfma_f32_16x16x32_bf16(a1, b1, acc[nt], 0, 0, 0);
        }
    }
    const int m = bm + w * 16 + quad * 4;
#pragma unroll
    for (int nt = 0; nt < 4; ++nt) {
        const int d = bn + nt * 16 + l15;
        const float bias = ob[d];
#pragma unroll
        for (int reg = 0; reg < 4; ++reg)
            out[(m + reg) * 512 + d] = acc[nt][reg] + bias + x[(m + reg) * 512 + d];
    }
}

extern "C" void kernel_launch(void* const* d_in, const int* in_sizes, int n_in,
                              void* d_out, int out_size, void* d_ws, size_t ws_size,
                              hipStream_t stream) {
    const float* x = (const float*)d_in[0];       // [6400,512]
    const float* uvqk = (const float*)d_in[1];    // [512,1024]
    const float* ow = (const float*)d_in[2];      // [512,256]
    const float* ob = (const float*)d_in[3];      // [512]
    const float* tsw = (const float*)d_in[4];     // [129]
    const int* ts = (const int*)d_in[5];          // [4,2048]
    // d_in[6] invalid_attn_mask: pure tril -> implemented as m<=n, not read
    const int* offs = (const int*)d_in[7];        // [5]
    float* out = (float*)d_out;                   // [6400,512]

    float* ws = (float*)d_ws;
    float* u = ws;                                // 6400*256 f32
    float* attn = u + 6400 * 256;                 // 6400*256 f32
    unsigned short* xnb = (unsigned short*)(attn + 6400 * 256);  // 6400*512 bf16
    unsigned short* hb = xnb + 6400 * 512;        // 6400*768 bf16
    unsigned short* o_in = hb + 6400 * 768;       // 6400*256 bf16
    unsigned short* uvqkT = o_in + 6400 * 256;    // 1024*512 bf16
    unsigned short* owb = uvqkT + 1024 * 512;     // 512*256 bf16
    // total ws use: ~32 MB

    k0a_transpose_cast<<<dim3(16, 8), 256, 0, stream>>>(uvqk, uvqkT);
    k0b_cast_ow<<<64, 256, 0, stream>>>(ow, owb);
    k1_ln<<<6400, 256, 0, stream>>>(x, xnb);
    k2_gemm1<<<dim3(16, 100), 256, 0, stream>>>(xnb, uvqkT, u, hb);
    k3_attn<<<dim3(32, 4, 4), 256, 0, stream>>>(hb, ts, tsw, offs, attn);
    k4a_ln<<<6400, 256, 0, stream>>>(attn, u, o_in);
    k4b_gemm2<<<dim3(8, 100), 256, 0, stream>>>(o_in, owb, ob, x, out);
}

// Round 5
// 189.471 us; speedup vs baseline: 3.8246x; 1.2316x over previous
//
#include <hip/hip_runtime.h>
#include <math.h>

// Problem constants (fixed by reference):
// B=4, N=2048, D=512, H=4, LH=AH=64, T=6400, lengths {2048,1536,1024,1792} (all %64==0)
// hb (bf16, 768 cols): v[0:256) q[256:512) k[512:768), head hd at +hd*64
// K3 split-K: CH=8 key tiles per chunk, max 4 chunks (qt<=31)

typedef __attribute__((ext_vector_type(8))) short bf16x8;   // 8 bf16 in 4 VGPRs
typedef __attribute__((ext_vector_type(4))) float f32x4;

__device__ __forceinline__ float silu_f(float v) {
    return v / (1.0f + __expf(-v));
}

__device__ __forceinline__ unsigned short f2bf(float f) {  // RNE float->bf16
    unsigned int u = __float_as_uint(f);
    u += 0x7fffu + ((u >> 16) & 1u);
    return (unsigned short)(u >> 16);
}

// ---------------- K0a: uvqkT[n][k] = bf16(uvqk[k][n])  (512x1024 -> 1024x512) ----------------
__global__ __launch_bounds__(256) void k0a_transpose_cast(const float* __restrict__ uvqk,
                                                          unsigned short* __restrict__ uvqkT) {
    __shared__ float L[64][68];
    const int n0 = blockIdx.x * 64;
    const int k0 = blockIdx.y * 64;
    const int tid = threadIdx.x;
#pragma unroll
    for (int i = 0; i < 4; ++i) {
        const int r = (tid >> 4) + i * 16;
        const int c = (tid & 15) * 4;
        *(float4*)&L[r][c] = *(const float4*)(uvqk + (k0 + r) * 1024 + n0 + c);
    }
    __syncthreads();
    const int n = tid >> 2;
    const int kb = (tid & 3) * 16;
#pragma unroll
    for (int pass = 0; pass < 2; ++pass) {
        unsigned short pk[8];
#pragma unroll
        for (int j = 0; j < 8; ++j) pk[j] = f2bf(L[kb + pass * 8 + j][n]);
        *(uint4*)(uvqkT + (n0 + n) * 512 + k0 + kb + pass * 8) = *(const uint4*)pk;
    }
}

// ---------------- K0b: owb = bf16(ow)  (512x256, already [d][k] k-contiguous) ----------------
__global__ __launch_bounds__(256) void k0b_cast_ow(const float* __restrict__ ow,
                                                   unsigned short* __restrict__ owb) {
    const int base = (blockIdx.x * 256 + threadIdx.x) * 8;
    float4 a = *(const float4*)(ow + base);
    float4 b = *(const float4*)(ow + base + 4);
    unsigned short pk[8] = {f2bf(a.x), f2bf(a.y), f2bf(a.z), f2bf(a.w),
                            f2bf(b.x), f2bf(b.y), f2bf(b.z), f2bf(b.w)};
    *(uint4*)(owb + base) = *(const uint4*)pk;
}

// ---------------- K1: xnb = bf16(layernorm(x)) over D=512 ----------------
__global__ __launch_bounds__(256) void k1_ln(const float* __restrict__ x,
                                             unsigned short* __restrict__ xnb) {
    const int row = blockIdx.x;
    const int tid = threadIdx.x;
    const float* xr = x + row * 512;
    float a = xr[tid];
    float b = xr[tid + 256];
    float s = a + b, ss = a * a + b * b;
#pragma unroll
    for (int off = 32; off > 0; off >>= 1) {
        s += __shfl_down(s, off);
        ss += __shfl_down(ss, off);
    }
    __shared__ float red[8];
    if ((tid & 63) == 0) { red[tid >> 6] = s; red[4 + (tid >> 6)] = ss; }
    __syncthreads();
    s = red[0] + red[1] + red[2] + red[3];
    ss = red[4] + red[5] + red[6] + red[7];
    const float mean = s * (1.0f / 512.0f);
    const float var = ss * (1.0f / 512.0f) - mean * mean;  // biased, matches jnp.var
    const float rstd = rsqrtf(var + 1e-6f);
    xnb[row * 512 + tid] = f2bf((a - mean) * rstd);
    xnb[row * 512 + tid + 256] = f2bf((b - mean) * rstd);
}

// ---------------- K2: h = silu(xn @ uvqk) via bf16 MFMA; u -> fp32, v/q/k -> bf16 ----------------
__global__ __launch_bounds__(256, 4) void k2_gemm1(const unsigned short* __restrict__ A,
                                                   const unsigned short* __restrict__ Bt,
                                                   float* __restrict__ u_out,
                                                   unsigned short* __restrict__ hb) {
    __shared__ __align__(16) unsigned short As[64][72];
    __shared__ __align__(16) unsigned short Bs[64][72];  // [n][k]
    const int tid = threadIdx.x;
    const int lane = tid & 63;
    const int w = tid >> 6;
    const int l15 = lane & 15;
    const int quad = lane >> 4;
    const int bm = blockIdx.y * 64;
    const int bn = blockIdx.x * 64;

    f32x4 acc[4] = {};
    for (int kc = 0; kc < 512; kc += 64) {
        __syncthreads();
#pragma unroll
        for (int i = 0; i < 2; ++i) {
            const int r = (tid >> 3) + i * 32;
            const int c = (tid & 7) * 8;
            *(uint4*)&As[r][c] = *(const uint4*)(A + (bm + r) * 512 + kc + c);
            *(uint4*)&Bs[r][c] = *(const uint4*)(Bt + (bn + r) * 512 + kc + c);
        }
        __syncthreads();
        const bf16x8 a0 = *(const bf16x8*)&As[w * 16 + l15][quad * 8];
        const bf16x8 a1 = *(const bf16x8*)&As[w * 16 + l15][32 + quad * 8];
#pragma unroll
        for (int nt = 0; nt < 4; ++nt) {
            bf16x8 b0 = *(const bf16x8*)&Bs[nt * 16 + l15][quad * 8];
            bf16x8 b1 = *(const bf16x8*)&Bs[nt * 16 + l15][32 + quad * 8];
            acc[nt] = __builtin_amdgcn_mfma_f32_16x16x32_bf16(a0, b0, acc[nt], 0, 0, 0);
            acc[nt] = __builtin_amdgcn_mfma_f32_16x16x32_bf16(a1, b1, acc[nt], 0, 0, 0);
        }
    }
    const int m = bm + w * 16 + quad * 4;
    if (bn < 256) {
#pragma unroll
        for (int nt = 0; nt < 4; ++nt)
#pragma unroll
            for (int reg = 0; reg < 4; ++reg)
                u_out[(m + reg) * 256 + bn + nt * 16 + l15] = silu_f(acc[nt][reg]);
    } else {
#pragma unroll
        for (int nt = 0; nt < 4; ++nt)
#pragma unroll
            for (int reg = 0; reg < 4; ++reg)
                hb[(m + reg) * 768 + (bn - 256) + nt * 16 + l15] = f2bf(silu_f(acc[nt][reg]));
    }
}

// ---------------- K3: fused jagged SiLU attention, split-K over key tiles ----------------
// blockIdx.x in [0,128): qt = x & 31, chunk c = x >> 5; chunk covers kt in [c*8, min(qt, c*8+7)]
// Partial O (fp32) stored to part[c][row][col]; K4a sums the valid chunks.
__global__ __launch_bounds__(256, 4) void k3_attn(const unsigned short* __restrict__ hb,
                                                  const int* __restrict__ ts,
                                                  const float* __restrict__ tsw,
                                                  const int* __restrict__ offs,
                                                  float* __restrict__ part) {
    const int qt = blockIdx.x & 31;
    const int c = blockIdx.x >> 5;
    const int b = blockIdx.y;
    const int hd = blockIdx.z;
    const int off = offs[b];
    const int len = offs[b + 1] - off;
    const int nqt = len >> 6;
    if (qt >= nqt || c * 8 > qt) return;
    const int q0 = qt * 64;
    const int kt_lo = c * 8;
    const int kt_hi = min(qt, c * 8 + 7);

    __shared__ __align__(16) unsigned short Qs[64][72];
    __shared__ __align__(16) unsigned short Ks[64][72];
    __shared__ __align__(16) unsigned short Vt[64][72];  // [lh][key]
    __shared__ __align__(16) unsigned short Ps[64][72];  // [query][key]
    __shared__ float tqf[64], tkf[64];
    __shared__ float tw[132];

    const int tid = threadIdx.x;
    const int lane = tid & 63;
    const int w = tid >> 6;
    const int l15 = lane & 15;
    const int quad = lane >> 4;

    if (tid < 129) tw[tid] = tsw[tid];
    if (tid < 64) tqf[tid] = (float)ts[b * 2048 + q0 + tid];
#pragma unroll
    for (int i = 0; i < 2; ++i) {
        const int r = (tid >> 3) + i * 32;
        const int cc = (tid & 7) * 8;
        *(uint4*)&Qs[r][cc] = *(const uint4*)(hb + (off + q0 + r) * 768 + 256 + hd * 64 + cc);
    }
    __syncthreads();

    const bf16x8 aQ0 = *(const bf16x8*)&Qs[w * 16 + l15][quad * 8];
    const bf16x8 aQ1 = *(const bf16x8*)&Qs[w * 16 + l15][32 + quad * 8];
    const f32x4 tq4 = *(const f32x4*)&tqf[w * 16 + quad * 4];
    const int nbase = q0 + w * 16 + quad * 4;

    f32x4 oacc[4] = {};

    for (int kt = kt_lo; kt <= kt_hi; ++kt) {
        const int m0 = kt * 64;
        __syncthreads();
#pragma unroll
        for (int i = 0; i < 2; ++i) {
            const int r = (tid >> 3) + i * 32;
            const int cc = (tid & 7) * 8;
            *(uint4*)&Ks[r][cc] = *(const uint4*)(hb + (off + m0 + r) * 768 + 512 + hd * 64 + cc);
            uint4 vv = *(const uint4*)(hb + (off + m0 + r) * 768 + hd * 64 + cc);
            const unsigned short* vs = (const unsigned short*)&vv;
#pragma unroll
            for (int j = 0; j < 8; ++j) Vt[cc + j][r] = vs[j];  // transpose V
        }
        if (tid < 64) tkf[tid] = (float)ts[b * 2048 + m0 + tid];
        __syncthreads();

        f32x4 s[4] = {};
#pragma unroll
        for (int nt = 0; nt < 4; ++nt) {
            bf16x8 b0 = *(const bf16x8*)&Ks[nt * 16 + l15][quad * 8];
            bf16x8 b1 = *(const bf16x8*)&Ks[nt * 16 + l15][32 + quad * 8];
            s[nt] = __builtin_amdgcn_mfma_f32_16x16x32_bf16(aQ0, b0, s[nt], 0, 0, 0);
            s[nt] = __builtin_amdgcn_mfma_f32_16x16x32_bf16(aQ1, b1, s[nt], 0, 0, 0);
        }

        const bool diag = (kt == qt);
#pragma unroll
        for (int nt = 0; nt < 4; ++nt) {
            const int m = m0 + nt * 16 + l15;
            const float tk = tkf[nt * 16 + l15];
#pragma unroll
            for (int reg = 0; reg < 4; ++reg) {
                const float delta = fabsf(tq4[reg] - tk);
                int bucket = (int)floorf(__log2f(1.0f + delta) * 0.6931471805599453f);
                bucket = bucket < 0 ? 0 : (bucket > 128 ? 128 : bucket);
                float val = s[nt][reg] + tw[bucket];
                val = silu_f(val) * (1.0f / 2048.0f);
                if (diag) val = (m <= nbase + reg) ? val : 0.0f;
                Ps[w * 16 + quad * 4 + reg][nt * 16 + l15] = f2bf(val);
            }
        }
        // wave reads back only its own Ps rows -> no barrier needed

        const bf16x8 aP0 = *(const bf16x8*)&Ps[w * 16 + l15][quad * 8];
        const bf16x8 aP1 = *(const bf16x8*)&Ps[w * 16 + l15][32 + quad * 8];
#pragma unroll
        for (int nt = 0; nt < 4; ++nt) {
            bf16x8 v0 = *(const bf16x8*)&Vt[nt * 16 + l15][quad * 8];
            bf16x8 v1 = *(const bf16x8*)&Vt[nt * 16 + l15][32 + quad * 8];
            oacc[nt] = __builtin_amdgcn_mfma_f32_16x16x32_bf16(aP0, v0, oacc[nt], 0, 0, 0);
            oacc[nt] = __builtin_amdgcn_mfma_f32_16x16x32_bf16(aP1, v1, oacc[nt], 0, 0, 0);
        }
    }

    float* pc = part + (size_t)c * (6400 * 256);
#pragma unroll
    for (int nt = 0; nt < 4; ++nt)
#pragma unroll
        for (int reg = 0; reg < 4; ++reg)
            pc[(off + q0 + w * 16 + quad * 4 + reg) * 256 + hd * 64 + nt * 16 + l15] =
                oacc[nt][reg];
}

// ---------------- K4a: o_in = bf16(u * layernorm(sum_c part[c])) over 256 ----------------
__global__ __launch_bounds__(256) void k4a_ln(const float* __restrict__ part,
                                              const float* __restrict__ u_in,
                                              const int* __restrict__ token_pos,
                                              unsigned short* __restrict__ o_in) {
    const int row = blockIdx.x;
    const int tid = threadIdx.x;
    const int qt = token_pos[row] >> 6;
    const int nch = (qt + 8) >> 3;  // ceil((qt+1)/8)
    float a = 0.0f;
    for (int c = 0; c < nch; ++c) a += part[(size_t)c * (6400 * 256) + row * 256 + tid];
    float s = a, ss = a * a;
#pragma unroll
    for (int off = 32; off > 0; off >>= 1) {
        s += __shfl_down(s, off);
        ss += __shfl_down(ss, off);
    }
    __shared__ float red[8];
    if ((tid & 63) == 0) { red[tid >> 6] = s; red[4 + (tid >> 6)] = ss; }
    __syncthreads();
    s = red[0] + red[1] + red[2] + red[3];
    ss = red[4] + red[5] + red[6] + red[7];
    const float mean = s * (1.0f / 256.0f);
    const float var = ss * (1.0f / 256.0f) - mean * mean;
    const float rstd = rsqrtf(var + 1e-6f);
    const float u = u_in[row * 256 + tid];
    o_in[row * 256 + tid] = f2bf(u * (a - mean) * rstd);
}

// ---------------- K4b: out = o_in @ o_w^T + o_b + x via bf16 MFMA ----------------
__global__ __launch_bounds__(256, 4) void k4b_gemm2(const unsigned short* __restrict__ A,
                                                    const unsigned short* __restrict__ owb,
                                                    const float* __restrict__ ob,
                                                    const float* __restrict__ x,
                                                    float* __restrict__ out) {
    __shared__ __align__(16) unsigned short As[64][72];
    __shared__ __align__(16) unsigned short Bs[64][72];  // [d][k]
    const int tid = threadIdx.x;
    const int lane = tid & 63;
    const int w = tid >> 6;
    const int l15 = lane & 15;
    const int quad = lane >> 4;
    const int bm = blockIdx.y * 64;
    const int bn = blockIdx.x * 64;

    f32x4 acc[4] = {};
    for (int kc = 0; kc < 256; kc += 64) {
        __syncthreads();
#pragma unroll
        for (int i = 0; i < 2; ++i) {
            const int r = (tid >> 3) + i * 32;
            const int c = (tid & 7) * 8;
            *(uint4*)&As[r][c] = *(const uint4*)(A + (bm + r) * 256 + kc + c);
            *(uint4*)&Bs[r][c] = *(const uint4*)(owb + (bn + r) * 256 + kc + c);
        }
        __syncthreads();
        const bf16x8 a0 = *(const bf16x8*)&As[w * 16 + l15][quad * 8];
        const bf16x8 a1 = *(const bf16x8*)&As[w * 16 + l15][32 + quad * 8];
#pragma unroll
        for (int nt = 0; nt < 4; ++nt) {
            bf16x8 b0 = *(const bf16x8*)&Bs[nt * 16 + l15][quad * 8];
            bf16x8 b1 = *(const bf16x8*)&Bs[nt * 16 + l15][32 + quad * 8];
            acc[nt] = __builtin_amdgcn_mfma_f32_16x16x32_bf16(a0, b0, acc[nt], 0, 0, 0);
            acc[nt] = __builtin_amdgcn_mfma_f32_16x16x32_bf16(a1, b1, acc[nt], 0, 0, 0);
        }
    }
    const int m = bm + w * 16 + quad * 4;
#pragma unroll
    for (int nt = 0; nt < 4; ++nt) {
        const int d = bn + nt * 16 + l15;
        const float bias = ob[d];
#pragma unroll
        for (int reg = 0; reg < 4; ++reg)
            out[(m + reg) * 512 + d] = acc[nt][reg] + bias + x[(m + reg) * 512 + d];
    }
}

extern "C" void kernel_launch(void* const* d_in, const int* in_sizes, int n_in,
                              void* d_out, int out_size, void* d_ws, size_t ws_size,
                              hipStream_t stream) {
    const float* x = (const float*)d_in[0];       // [6400,512]
    const float* uvqk = (const float*)d_in[1];    // [512,1024]
    const float* ow = (const float*)d_in[2];      // [512,256]
    const float* ob = (const float*)d_in[3];      // [512]
    const float* tsw = (const float*)d_in[4];     // [129]
    const int* ts = (const int*)d_in[5];          // [4,2048]
    // d_in[6] invalid_attn_mask: pure tril -> implemented as m<=n, not read
    const int* offs = (const int*)d_in[7];        // [5]
    // d_in[8] token_batch (unused)
    const int* token_pos = (const int*)d_in[9];   // [6400]
    float* out = (float*)d_out;                   // [6400,512]

    float* ws = (float*)d_ws;
    float* u = ws;                                // 6400*256 f32
    float* part = u + 6400 * 256;                 // 4*6400*256 f32 (split-K partials)
    unsigned short* xnb = (unsigned short*)(part + 4 * 6400 * 256);  // 6400*512 bf16
    unsigned short* hb = xnb + 6400 * 512;        // 6400*768 bf16
    unsigned short* o_in = hb + 6400 * 768;       // 6400*256 bf16
    unsigned short* uvqkT = o_in + 6400 * 256;    // 1024*512 bf16
    unsigned short* owb = uvqkT + 1024 * 512;     // 512*256 bf16
    // total ws use: ~54 MB

    k0a_transpose_cast<<<dim3(16, 8), 256, 0, stream>>>(uvqk, uvqkT);
    k0b_cast_ow<<<64, 256, 0, stream>>>(ow, owb);
    k1_ln<<<6400, 256, 0, stream>>>(x, xnb);
    k2_gemm1<<<dim3(16, 100), 256, 0, stream>>>(xnb, uvqkT, u, hb);
    k3_attn<<<dim3(128, 4, 4), 256, 0, stream>>>(hb, ts, tsw, offs, part);
    k4a_ln<<<6400, 256, 0, stream>>>(part, u, token_pos, o_in);
    k4b_gemm2<<<dim3(8, 100), 256, 0, stream>>>(o_in, owb, ob, x, out);
}